// Round 11
// baseline (139.462 us; speedup 1.0000x reference)
//
#include <hip/hip_runtime.h>

// ---------------------------------------------------------------------------
// MHA block: q,k,v = x@W*.T + b*; causal softmax attention; out = preout@Wo.T+bo
// B=2, S=2048, D=1024, NH=16, HD=64. fp32 I/O, bf16 internal (MFMA everywhere).
// Round 11: attention on 32x32x16 MFMA — 32 queries/wave, 2-wave (128-thr)
//           blocks, same grid (32,32). Per-query LDS reads and MFMA issue
//           halve; per-query register state unchanged vs r10.
// ---------------------------------------------------------------------------

#define DEV __device__ __forceinline__

typedef __bf16 bf16x8 __attribute__((ext_vector_type(8)));
typedef float  f32x4  __attribute__((ext_vector_type(4)));
typedef float  f32x16 __attribute__((ext_vector_type(16)));
typedef unsigned short u16;
typedef u16 u16x8 __attribute__((ext_vector_type(8)));
typedef u16 u16x4 __attribute__((ext_vector_type(4)));

constexpr int BB  = 2;
constexpr int S   = 2048;
constexpr int DM  = 1024;
constexpr int NH  = 16;
constexpr int MT  = BB * S;      // 4096 token rows
constexpr int LDQ = 3 * DM;      // fused QKV row stride (3072)

DEV u16 f2bf(float f) {
    unsigned u = __float_as_uint(f);
    unsigned r = u + 0x7fffu + ((u >> 16) & 1u);   // RNE
    return (u16)(r >> 16);
}

DEV unsigned cvt_pk_bf16(float lo, float hi) {
    unsigned r;
    asm("v_cvt_pk_bf16_f32 %0, %1, %2" : "=v"(r) : "v"(lo), "v"(hi));
    return r;
}

typedef const __attribute__((address_space(1))) void* gas_t;
typedef __attribute__((address_space(3))) void* las_t;
DEV void gl16(const u16* g, u16* l) {
    __builtin_amdgcn_global_load_lds((gas_t)g, (las_t)l, 16, 0, 0);
}

// ---------------------------------------------------------------------------
// fused fp32 -> bf16 convert: x (MT*DM) then 4 weight matrices (4*DM*DM)
// ---------------------------------------------------------------------------
__global__ void cvt_all(const float* __restrict__ x,
                        const float* __restrict__ w0, const float* __restrict__ w1,
                        const float* __restrict__ w2, const float* __restrict__ w3,
                        u16* __restrict__ xb, u16* __restrict__ wb) {
    const int idx = blockIdx.x * 256 + threadIdx.x;
    constexpr int NX4 = (MT * DM) / 4;          // 1048576 float4 chunks of x
    if (idx < NX4) {
        float4 v = reinterpret_cast<const float4*>(x)[idx];
        u16x4 o;
        o[0] = f2bf(v.x); o[1] = f2bf(v.y); o[2] = f2bf(v.z); o[3] = f2bf(v.w);
        reinterpret_cast<u16x4*>(xb)[idx] = o;
    } else {
        const int wi  = idx - NX4;              // 0 .. 4*262144-1
        const int wid = wi >> 18;
        const int sub = wi & 0x3FFFF;
        const float* src = (wid == 0) ? w0 : (wid == 1) ? w1 : (wid == 2) ? w2 : w3;
        float4 v = reinterpret_cast<const float4*>(src)[sub];
        u16x4 o;
        o[0] = f2bf(v.x); o[1] = f2bf(v.y); o[2] = f2bf(v.z); o[3] = f2bf(v.w);
        reinterpret_cast<u16x4*>(wb)[wi] = o;
    }
}

// ---------------------------------------------------------------------------
// GEMM (m97 structure + 2-phase dbuf + XCD swizzle): C = A @ W^T + bias, *scale.
// 128x128 tile, BK=32, 4 waves; global_load_lds staging overlapped with MFMA.
// VT=true: column-segment >= 2048 (V head outputs) written TRANSPOSED to
// Vtg[bh][d][S] as packed 8B stores. gridDim.x MUST be 32; nwg % 8 == 0.
// ---------------------------------------------------------------------------
template <bool OUT_BF16, bool VT>
__global__ __launch_bounds__(256) void gemm_lds(const u16* __restrict__ A,
                                                const u16* __restrict__ W,
                                                const float* __restrict__ b0,
                                                const float* __restrict__ b1,
                                                const float* __restrict__ b2,
                                                float sc0, float sc1, float sc2,
                                                void* __restrict__ Cout,
                                                u16* __restrict__ Vtg,
                                                int K, int ldc) {
    __shared__ __align__(16) u16 Al[2][128 * 32];
    __shared__ __align__(16) u16 Bl[2][128 * 32];

    const int tid  = threadIdx.x;
    const int lane = tid & 63;
    const int w    = tid >> 6;
    const int ln   = lane & 15;
    const int g    = lane >> 4;
    const int kg8  = g * 8;
    const int wr   = w >> 1, wc = w & 1;

    const int lin = blockIdx.x + 32 * blockIdx.y;
    const int nq  = (32 * gridDim.y) >> 3;
    const int sw  = (lin & 7) * nq + (lin >> 3);
    const int m0  = (sw & 31) * 128;
    const int n0  = (sw >> 5) * 128;

    const float* bias; int nb; float scl;
    if (n0 >= 2048)      { bias = b2; nb = n0 - 2048; scl = sc2; }
    else if (n0 >= 1024) { bias = b1; nb = n0 - 1024; scl = sc1; }
    else                 { bias = b0; nb = n0;        scl = sc0; }

    const int r_  = tid >> 2;
    const int c8_ = (tid & 3) << 3;
    const u16* gA0 = A + (size_t)(m0 + r_) * K + c8_;
    const u16* gA1 = gA0 + (size_t)64 * K;
    const u16* gW0 = W + (size_t)(n0 + r_) * K + c8_;
    const u16* gW1 = gW0 + (size_t)64 * K;

    f32x4 acc[4][4] = {};

    gl16(gA0, &Al[0][tid * 8]);
    gl16(gA1, &Al[0][2048 + tid * 8]);
    gl16(gW0, &Bl[0][tid * 8]);
    gl16(gW1, &Bl[0][2048 + tid * 8]);

    int cur = 0;
    for (int kb = 0; kb < K; kb += 32) {
        const bool more = (kb + 32 < K);
        if (more) {
            u16* a = &Al[cur ^ 1][0];
            u16* b = &Bl[cur ^ 1][0];
            gl16(gA0 + kb + 32, a + tid * 8);
            gl16(gA1 + kb + 32, a + 2048 + tid * 8);
            gl16(gW0 + kb + 32, b + tid * 8);
            gl16(gW1 + kb + 32, b + 2048 + tid * 8);
            asm volatile("s_waitcnt vmcnt(4)" ::: "memory");
        } else {
            asm volatile("s_waitcnt vmcnt(0)" ::: "memory");
        }
        __syncthreads();

        bf16x8 ar[4], br[4];
        #pragma unroll
        for (int i = 0; i < 4; ++i)
            ar[i] = *reinterpret_cast<const bf16x8*>(&Al[cur][(wr * 64 + i * 16 + ln) * 32 + kg8]);
        #pragma unroll
        for (int j = 0; j < 4; ++j)
            br[j] = *reinterpret_cast<const bf16x8*>(&Bl[cur][(wc * 64 + j * 16 + ln) * 32 + kg8]);
        #pragma unroll
        for (int i = 0; i < 4; ++i)
            #pragma unroll
            for (int j = 0; j < 4; ++j)
                acc[i][j] = __builtin_amdgcn_mfma_f32_16x16x32_bf16(ar[i], br[j], acc[i][j], 0, 0, 0);
        __syncthreads();
        cur ^= 1;
    }

    float bv[4];
    #pragma unroll
    for (int j = 0; j < 4; ++j) bv[j] = bias[nb + wc * 64 + j * 16 + ln];

    if (VT && n0 >= 2048) {
        // V segment -> transposed global: Vtg[(b*16+h)*64+d][s], packed 4 tokens
        #pragma unroll
        for (int i = 0; i < 4; ++i)
            #pragma unroll
            for (int j = 0; j < 4; ++j) {
                const int col  = (n0 - 2048) + wc * 64 + j * 16 + ln;  // 0..1023
                const int h    = col >> 6, d = col & 63;
                const int row0 = m0 + wr * 64 + i * 16 + g * 4;
                const int bb   = row0 >> 11, s0 = row0 & 2047;
                u16x4 pk;
                #pragma unroll
                for (int r = 0; r < 4; ++r) pk[r] = f2bf(acc[i][j][r] + bv[j]);
                *reinterpret_cast<u16x4*>(
                    &Vtg[((size_t)((bb * 16 + h) * 64 + d)) * S + s0]) = pk;
            }
        return;
    }

    #pragma unroll
    for (int i = 0; i < 4; ++i)
        #pragma unroll
        for (int j = 0; j < 4; ++j) {
            const int col = n0 + wc * 64 + j * 16 + ln;
            #pragma unroll
            for (int r = 0; r < 4; ++r) {
                const int row = m0 + wr * 64 + i * 16 + g * 4 + r;
                const float v = (acc[i][j][r] + bv[j]) * scl;
                if (OUT_BF16)
                    ((u16*)Cout)[(size_t)row * ldc + col] = f2bf(v);
                else
                    ((float*)Cout)[(size_t)row * ldc + col] = v;
            }
        }
}

// ---------------------------------------------------------------------------
// Causal flash attention, swapped-QK^T on 32x32x16 MFMA.
// 128 thr = 2 waves; wave owns 32 queries (lane owns query lane&31).
// QK^T = mfma32(Kfrag, Qfrag): C[row=key (r&3)+8(r>>2)+4hi (+32blk)][col=query].
// Per-lane softmax over 32 regs + 1 shfl_xor(32); defer-max (thr 8, log2).
// P: cvt_pk pairs -> Pl[w][q][68]; PV = mfma32(Pfrag, Vtfrag) (C row=query,
// col=d). gl16-staged 64-key tiles, XOR chunk swizzle, dbuf + vmcnt(8).
// ---------------------------------------------------------------------------
__global__ __launch_bounds__(128) void attn_mfma(const u16* __restrict__ QKV,
                                                 const u16* __restrict__ Vtg,
                                                 u16* __restrict__ Pg) {
    const int bh = blockIdx.x;
    const int b  = bh >> 4, h = bh & 15;
    const int y  = blockIdx.y;
    const int qc = (y & 1) ? (31 - (y >> 1)) : (y >> 1);
    const int q0 = qc * 64;
    const int tid  = threadIdx.x;    // 0..127
    const int w    = tid >> 6;       // wave 0..1
    const int lane = tid & 63;
    const int ql   = lane & 31;      // query (C col)
    const int hi   = lane >> 5;      // frag half
    const int xq   = ql & 7;         // row-XOR for K/V chunk reads

    __shared__ __align__(16) u16 Kbuf[2][64 * 64];
    __shared__ __align__(16) u16 Vbuf[2][64 * 64];   // rows = d, cols = key
    __shared__ __align__(16) u16 Pl[2][32][68];

    // staging: 128 thr x 4 chunks; chunk = it*128+tid; row = r0+it*16, slot=tid&7
    const int slot = tid & 7;
    const int r0   = tid >> 3;                       // 0..15
    const int xr0  = (slot ^ (r0 & 7)) << 3;         // (r0+16it)&7 == r0&7
    const size_t kRowBase = (size_t)(b * S) * LDQ + DM + h * 64;
    const size_t vRowBase = (size_t)(bh * 64) * S;

    // Q fragments (B operand): col = ql, k-elems d = ks*16 + hi*8 .. +7
    bf16x8 qf[4];
    #pragma unroll
    for (int ks = 0; ks < 4; ++ks)
        qf[ks] = *reinterpret_cast<const bf16x8*>(
            &QKV[(size_t)(b * S + q0 + w * 32 + ql) * LDQ + h * 64 + ks * 16 + hi * 8]);

    f32x16 o0 = {}, o1 = {};         // C: row=query(reg map), col=d (ql) / d+32
    float m = -1e30f, l = 0.0f;      // softmax state of query ql

    const int ntiles = qc + 1;

    // prologue: stage tile 0 into buf 0
    #pragma unroll
    for (int it = 0; it < 4; ++it) {
        gl16(&QKV[kRowBase + (size_t)(r0 + it * 16) * LDQ + xr0], &Kbuf[0][(it * 128 + tid) * 8]);
        gl16(&Vtg[vRowBase + (size_t)(r0 + it * 16) * S + xr0],   &Vbuf[0][(it * 128 + tid) * 8]);
    }

    // strength-reduced next-tile pointers
    const u16* kp[4];
    const u16* vp[4];
    #pragma unroll
    for (int it = 0; it < 4; ++it) {
        kp[it] = QKV + kRowBase + (size_t)(64 + r0 + it * 16) * LDQ + xr0;
        vp[it] = Vtg + vRowBase + (size_t)(r0 + it * 16) * S + 64 + xr0;
    }
    constexpr size_t kstep = (size_t)64 * LDQ;
    constexpr size_t vstep = 64;

    int cur = 0;
    for (int t = 0; t < ntiles; ++t) {
        const bool more = (t + 1 < ntiles);
        if (more) {
            u16* kb = &Kbuf[cur ^ 1][0];
            u16* vb = &Vbuf[cur ^ 1][0];
            #pragma unroll
            for (int it = 0; it < 4; ++it) {
                gl16(kp[it], kb + (it * 128 + tid) * 8);
                gl16(vp[it], vb + (it * 128 + tid) * 8);
                kp[it] += kstep; vp[it] += vstep;
            }
            asm volatile("s_waitcnt vmcnt(8)" ::: "memory");
        } else {
            asm volatile("s_waitcnt vmcnt(0)" ::: "memory");
        }
        __syncthreads();

        const u16* Kb = &Kbuf[cur][0];
        const u16* Vb = &Vbuf[cur][0];

        // ---- QK^T swapped: s0/s1 = key blocks 0/1 ----
        f32x16 s0 = {}, s1 = {};
        __builtin_amdgcn_s_setprio(1);
        #pragma unroll
        for (int ks = 0; ks < 4; ++ks) {
            const int c8 = ((ks << 1) | hi) ^ xq;
            bf16x8 kf0 = *reinterpret_cast<const bf16x8*>(&Kb[ql * 64 + c8 * 8]);
            bf16x8 kf1 = *reinterpret_cast<const bf16x8*>(&Kb[(32 + ql) * 64 + c8 * 8]);
            s0 = __builtin_amdgcn_mfma_f32_32x32x16_bf16(kf0, qf[ks], s0, 0, 0, 0);
            s1 = __builtin_amdgcn_mfma_f32_32x32x16_bf16(kf1, qf[ks], s1, 0, 0, 0);
        }
        __builtin_amdgcn_s_setprio(0);

        // ---- causal mask (diagonal tile only): key > query ----
        if (t == ntiles - 1) {
            const int dq = w * 32 + ql;
            const int h4 = 4 * hi;
            #pragma unroll
            for (int r = 0; r < 16; ++r) {
                const int k0 = (r & 3) + 8 * (r >> 2) + h4;
                if (k0 > dq)      s0[r] = -1e30f;
                if (k0 + 32 > dq) s1[r] = -1e30f;
            }
        }

        // ---- row max over 32 regs + partner half ----
        float tp[16];
        #pragma unroll
        for (int r = 0; r < 16; ++r) tp[r] = fmaxf(s0[r], s1[r]);
        #pragma unroll
        for (int st = 8; st >= 1; st >>= 1)
            #pragma unroll
            for (int r = 0; r < st; ++r) tp[r] = fmaxf(tp[r], tp[r + st]);
        float pm = tp[0];
        pm = fmaxf(pm, __shfl_xor(pm, 32, 64));

        const bool grew = __any(pm > m + 8.0f);
        float cr = 1.0f;
        if (grew) {
            const float mn = fmaxf(m, pm);
            cr = exp2f(m - mn);
            m = mn;
        }
        #pragma unroll
        for (int r = 0; r < 16; ++r) {
            s0[r] = exp2f(s0[r] - m);
            s1[r] = exp2f(s1[r] - m);
        }

        // ---- row sum (32 regs + partner half) ----
        float ta[16];
        #pragma unroll
        for (int r = 0; r < 16; ++r) ta[r] = s0[r] + s1[r];
        #pragma unroll
        for (int st = 8; st >= 1; st >>= 1)
            #pragma unroll
            for (int r = 0; r < st; ++r) ta[r] += ta[r + st];
        float ts = ta[0];
        ts += __shfl_xor(ts, 32, 64);
        l = grew ? (l * cr + ts) : (l + ts);

        // ---- P -> Pl[w][query ql][key]: cvt_pk uint2 runs of 4 keys ----
        #pragma unroll
        for (int rr = 0; rr < 4; ++rr) {
            uint2 p0, p1;
            p0.x = cvt_pk_bf16(s0[4 * rr + 0], s0[4 * rr + 1]);
            p0.y = cvt_pk_bf16(s0[4 * rr + 2], s0[4 * rr + 3]);
            *reinterpret_cast<uint2*>(&Pl[w][ql][8 * rr + 4 * hi]) = p0;
            p1.x = cvt_pk_bf16(s1[4 * rr + 0], s1[4 * rr + 1]);
            p1.y = cvt_pk_bf16(s1[4 * rr + 2], s1[4 * rr + 3]);
            *reinterpret_cast<uint2*>(&Pl[w][ql][32 + 8 * rr + 4 * hi]) = p1;
        }

        // ---- rescale O only when max grew (per-reg query broadcast) ----
        if (grew) {
            #pragma unroll
            for (int r = 0; r < 16; ++r) {
                const float crr = __shfl(cr, (r & 3) + 8 * (r >> 2) + 4 * hi, 64);
                o0[r] *= crr;
                o1[r] *= crr;
            }
        }

        // ---- PV: O += P @ Vt^T (C row=query, col=d) ----
        __builtin_amdgcn_s_setprio(1);
        #pragma unroll
        for (int ks = 0; ks < 4; ++ks) {
            const int c8 = ((ks << 1) | hi) ^ xq;
            bf16x8 pf  = *reinterpret_cast<const bf16x8*>(&Pl[w][ql][ks * 16 + hi * 8]);
            bf16x8 vf0 = *reinterpret_cast<const bf16x8*>(&Vb[ql * 64 + c8 * 8]);
            bf16x8 vf1 = *reinterpret_cast<const bf16x8*>(&Vb[(32 + ql) * 64 + c8 * 8]);
            o0 = __builtin_amdgcn_mfma_f32_32x32x16_bf16(pf, vf0, o0, 0, 0, 0);
            o1 = __builtin_amdgcn_mfma_f32_32x32x16_bf16(pf, vf1, o1, 0, 0, 0);
        }
        __builtin_amdgcn_s_setprio(0);

        __syncthreads();
        cur ^= 1;
    }

    // ---- epilogue: normalize (per-reg query broadcast of 1/l) and store ----
    const float linv = 1.0f / l;
    #pragma unroll
    for (int r = 0; r < 16; ++r) {
        const int qrow = (r & 3) + 8 * (r >> 2) + 4 * hi;
        const float inv = __shfl(linv, qrow, 64);
        const size_t base = (size_t)(b * S + q0 + w * 32 + qrow) * DM + h * 64;
        Pg[base + ql]      = f2bf(o0[r] * inv);
        Pg[base + 32 + ql] = f2bf(o1[r] * inv);
    }
}

// ---------------------------------------------------------------------------
// launch
// ---------------------------------------------------------------------------
extern "C" void kernel_launch(void* const* d_in, const int* in_sizes, int n_in,
                              void* d_out, int out_size, void* d_ws, size_t ws_size,
                              hipStream_t stream) {
    const float* x  = (const float*)d_in[0];
    const float* Wq = (const float*)d_in[1];
    const float* bq = (const float*)d_in[2];
    const float* Wk = (const float*)d_in[3];
    const float* bk = (const float*)d_in[4];
    const float* Wv = (const float*)d_in[5];
    const float* bv = (const float*)d_in[6];
    const float* Wo = (const float*)d_in[7];
    const float* bo = (const float*)d_in[8];
    float* out = (float*)d_out;

    u16* xb   = (u16*)d_ws;                      // MT*DM ; later aliased as Pb
    u16* wqb  = xb   + (size_t)MT * DM;          // 4 weights contiguous
    u16* wob  = wqb  + (size_t)3 * DM * DM;
    u16* QKVb = wob  + (size_t)DM * DM;          // MT*3DM (V third unused)
    u16* Vtg  = QKVb + (size_t)MT * 3 * DM;      // MT*DM
    u16* Pb   = xb;                              // alias: x no longer needed

    // fused converts: x + 4 weights, one dispatch
    cvt_all<<<dim3(8192), dim3(256), 0, stream>>>(x, Wq, Wk, Wv, Wo, xb, wqb);

    // fused QKV projection; Q segment scaled by 0.125*log2(e) for exp2 softmax;
    // V segment written transposed to Vtg by the epilogue (VT=true)
    const float SCL = 0.125f * 1.4426950408889634f;
    gemm_lds<true, true><<<dim3(MT / 128, 3 * DM / 128), dim3(256), 0, stream>>>(
        xb, wqb, bq, bk, bv, SCL, 1.0f, 1.0f, QKVb, Vtg, DM, LDQ);

    attn_mfma<<<dim3(BB * NH, S / 64), dim3(128), 0, stream>>>(QKVb, Vtg, Pb);

    gemm_lds<false, false><<<dim3(MT / 128, DM / 128), dim3(256), 0, stream>>>(
        Pb, wob, bo, bo, bo, 1.0f, 1.0f, 1.0f, out, nullptr, DM, DM);
}